// Round 12
// baseline (157.726 us; speedup 1.0000x reference)
//
#include <hip/hip_runtime.h>
#include <hip/hip_bf16.h>
#include <math.h>

namespace {
constexpr int B_N = 4, T_N = 128, P_N = 256, D_N = 512, S_N = 64;
constexpr int NTH = 512;
constexpr int KC  = 32;
constexpr int NCH = D_N / KC;   // 16 k-chunks

// LDS (bytes). Liveness (barrier-protected):
//   phase1 k-loop : XF0 [0,16384) XF1 [16384,32768) WS0 [32768,49152) WS1 [49152,65536)
//   epilogue+scan : BU [0,16384) + CHB [16384,32768) + ROS0 [32768,49152) (DMA during scan)
//   phase3        : ROS0 [32768,49152) / ROS1 [49152,65536) double-buffer + CHB
constexpr int XF0_OFF = 0;       // f32 [128][32] X chunk, 16B-unit source-swizzled (u^=r&7)
constexpr int XF1_OFF = 16384;
constexpr int WS0_OFF = 32768;   // bf16 [256][32] swz32 W image copy (rows 200-255 zero)
constexpr int WS1_OFF = 49152;
constexpr int BU_OFF  = 0;       // bf16 [128][64] linear: (B+bias)*u -> H (in place)
constexpr int CH_OFF  = 16384;   // bf16 [128][64] swz64: C+bias -> C*H
constexpr int ROS0_OFF= 32768;   // bf16 [128][64] swz64 ro image copy
constexpr int ROS1_OFF= 49152;
constexpr int DT_OFF  = 65536;   // f32 [128]
constexpr int LDS_BYTES = 66048; // 2 blocks/CU (132 KB <= 160 KB)

constexpr int WIMG_ELEMS  = NCH * 256 * 32;   // 16 x 16KB W chunk images
constexpr int ROIMG_ELEMS = 4 * 128 * 64;     // 4 x 16KB ro pass images
}

typedef short bf16x8 __attribute__((ext_vector_type(8)));
typedef float f32x4  __attribute__((ext_vector_type(4)));

__device__ __forceinline__ unsigned short f2b(float f) {
    unsigned int x = __float_as_uint(f);
    return (unsigned short)((x + 0x7FFFu + ((x >> 16) & 1u)) >> 16);  // RNE
}
__device__ __forceinline__ float b2f(unsigned short h) {
    return __uint_as_float(((unsigned int)h) << 16);
}
__device__ __forceinline__ unsigned int pk2(float lo, float hi) {
    union { __hip_bfloat162 h; unsigned int u; } cv;
    cv.h = __float22bfloat162_rn(float2{lo, hi});
    return cv.u;
}
__device__ __forceinline__ int swz32(int row, int col) {
    return row * 32 + (col ^ (((row >> 1) & 3) << 3));
}
__device__ __forceinline__ int swz64(int row, int col) {
    return row * 64 + (col ^ ((row & 7) << 3));
}
// async global->LDS DMA: per-lane global src, wave-uniform LDS dst (lane i -> dst+i*16)
__device__ __forceinline__ void gload16(const void* g, void* l) {
    __builtin_amdgcn_global_load_lds(
        (const __attribute__((address_space(1))) unsigned int*)g,
        (__attribute__((address_space(3))) unsigned int*)l, 16, 0, 0);
}
// build bf16x8 A-frag from fp32 X chunk in LDS (row R, logical units lg*2,lg*2+1;
// phys unit = u ^ (R&7), matching the DMA source swizzle; 2-way bank alias = free)
__device__ __forceinline__ bf16x8 xfrag(const char* XF, int R, int lg) {
    const int k = R & 7;
    const float4 fa = *(const float4*)(XF + R * 128 + (((lg * 2)    ) ^ k) * 16);
    const float4 fb = *(const float4*)(XF + R * 128 + (((lg * 2) + 1) ^ k) * 16);
    union { uint4 u; bf16x8 h; } cv;
    cv.u.x = pk2(fa.x, fa.y); cv.u.y = pk2(fa.z, fa.w);
    cv.u.z = pk2(fb.x, fb.y); cv.u.w = pk2(fb.z, fb.w);
    return cv.h;
}

// ===== K0: build swizzled bf16 images of weights and ro in ws =====
__global__ __launch_bounds__(512) void mamba_prep(
    const float* __restrict__ U_w, const float* __restrict__ sB_w,
    const float* __restrict__ sC_w, const float* __restrict__ sD1_w,
    const float* __restrict__ ro_w,
    unsigned short* __restrict__ wImg, unsigned short* __restrict__ roImg)
{
    const int idx = blockIdx.x * 512 + threadIdx.x;
    if (idx < WIMG_ELEMS) {
        const int kc = idx >> 13, rem = idx & 8191, r = rem >> 5, c = rem & 31;
        float v = 0.0f;
        if (r < 192) {
            const int g = r >> 4, w = r & 15, tr = g % 3, sb = g / 3;
            const float* base = (tr == 0) ? U_w : (tr == 1) ? sB_w : sC_w;
            v = base[(size_t)(sb * 16 + w) * D_N + kc * KC + c];
        } else if (r < 200) {
            v = sD1_w[(size_t)(r - 192) * D_N + kc * KC + c];
        }
        wImg[kc * 8192 + swz32(r, c)] = f2b(v);
    } else if (idx < WIMG_ELEMS + ROIMG_ELEMS) {
        const int j = idx - WIMG_ELEMS;
        const int pp = j >> 13, rem = j & 8191, r = rem >> 6, c = rem & 63;
        roImg[pp * 8192 + swz64(r, c)] = f2b(ro_w[(size_t)(pp * 128 + r) * S_N + c]);
    }
}

// ===== fused kernel =====
__global__ __launch_bounds__(NTH, 4) void mamba_mfma(
    const float* __restrict__ X, const float* __restrict__ H0,
    const float* __restrict__ a_hat,
    const float* __restrict__ sB_b, const float* __restrict__ sC_b,
    const float* __restrict__ sD1_b, const float* __restrict__ sD2_w,
    const float* __restrict__ sD2_b,
    const unsigned short* __restrict__ wImg, const unsigned short* __restrict__ roImg,
    float* __restrict__ Hseq, float* __restrict__ Y, float* __restrict__ HT)
{
    __shared__ __align__(16) char smem[LDS_BYTES];
    float* DTB = (float*)(smem + DT_OFF);

    const int tid  = threadIdx.x;
    const int lane = tid & 63;
    const int wid  = tid >> 6;
    const int wm   = wid >> 2;     // 0..1
    const int wn   = wid & 3;      // 0..3
    const int l15  = lane & 15;
    const int lg   = lane >> 4;    // 0..3
    const int lane16 = lane * 16;
    const int b    = blockIdx.x >> 8;
    const int p    = blockIdx.x & 255;
    const char* wImgB  = (const char*)wImg;
    const char* roImgB = (const char*)roImg;

    // scan-wave constants hoisted (issued early; hide under phase 1)
    const float la  = (tid < 64) ? -expf(a_hat[tid]) : 0.0f;
    const float h0v = (tid < 64) ? H0[((size_t)b * P_N + p) * S_N + tid] : 0.0f;

    // X DMA per-lane sources. Dest unit d = wid*128 + i*64 + lane; row r=d>>3;
    // this slot receives logical unit u=(d&7)^(r&7)  ->  read side XORs back.
    const int ldr0 = wid * 16 + (lane >> 3);               // row, DMA instr 0
    const int ldr1 = ldr0 + 8;                             // row, DMA instr 1
    const int ldu  = (lane & 7) ^ ((lane >> 3) & 7);       // logical 16B unit (both)
    const char* srcX0 = (const char*)(X + (((size_t)b * T_N + ldr0) * P_N + p) * D_N) + ldu * 16;
    const char* srcX1 = (const char*)(X + (((size_t)b * T_N + ldr1) * P_N + p) * D_N) + ldu * 16;

    // ---------------- Phase 1: projections, M=128(t) N=192(+8 dt) K=512 ----------------
    f32x4 acc[4][3];
    f32x4 accdt;
    #pragma unroll
    for (int q = 0; q < 4; ++q) accdt[q] = 0.0f;
    #pragma unroll
    for (int mf = 0; mf < 4; ++mf)
        #pragma unroll
        for (int nf = 0; nf < 3; ++nf)
            #pragma unroll
            for (int q = 0; q < 4; ++q) acc[mf][nf][q] = 0.0f;

    // prologue: DMA chunk 0 (X fp32 + W bf16)
    gload16(srcX0, smem + XF0_OFF + wid * 2048);
    gload16(srcX1, smem + XF0_OFF + wid * 2048 + 1024);
    gload16(wImgB + wid * 2048 + lane16,        smem + WS0_OFF + wid * 2048);
    gload16(wImgB + wid * 2048 + 1024 + lane16, smem + WS0_OFF + wid * 2048 + 1024);
    __syncthreads();

    const int kb = lg * 8;
    #pragma unroll 2
    for (int kc = 0; kc < NCH; ++kc) {
        const char*     XFc = smem + ((kc & 1) ? XF1_OFF : XF0_OFF);
        unsigned short* WSc = (unsigned short*)(smem + ((kc & 1) ? WS1_OFF : WS0_OFF));
        char*           XFn = smem + ((kc & 1) ? XF0_OFF : XF1_OFF);
        char*           WSn = smem + ((kc & 1) ? WS0_OFF : WS1_OFF);
        if (kc + 1 < NCH) {   // stage next chunk: 4 DMA instructions, zero VALU
            gload16(srcX0 + (kc + 1) * 128, XFn + wid * 2048);
            gload16(srcX1 + (kc + 1) * 128, XFn + wid * 2048 + 1024);
            gload16(wImgB + (kc + 1) * 16384 + wid * 2048 + lane16,        WSn + wid * 2048);
            gload16(wImgB + (kc + 1) * 16384 + wid * 2048 + 1024 + lane16, WSn + wid * 2048 + 1024);
        }
        __builtin_amdgcn_s_setprio(1);
        bf16x8 a[4];
        #pragma unroll
        for (int mf = 0; mf < 4; ++mf)
            a[mf] = xfrag(XFc, wm * 64 + mf * 16 + l15, lg);
        #pragma unroll
        for (int nf = 0; nf < 3; ++nf) {
            bf16x8 bb = *(const bf16x8*)&WSc[swz32(wn * 48 + nf * 16 + l15, kb)];
            #pragma unroll
            for (int mf = 0; mf < 4; ++mf)
                acc[mf][nf] = __builtin_amdgcn_mfma_f32_16x16x32_bf16(a[mf], bb, acc[mf][nf], 0, 0, 0);
        }
        {   // dt frag (W rows 192-199 sD1, 200-207 baked zeros)
            bf16x8 adt = xfrag(XFc, wid * 16 + l15, lg);
            bf16x8 bd  = *(const bf16x8*)&WSc[swz32(192 + l15, kb)];
            accdt = __builtin_amdgcn_mfma_f32_16x16x32_bf16(adt, bd, accdt, 0, 0, 0);
        }
        __builtin_amdgcn_s_setprio(0);
        __syncthreads();   // drains next-chunk DMA (vmcnt) + this chunk's LDS reads
    }

    // ---------------- Phase 1 epilogue ----------------
    // C/D frag: col=lane&15 (s), row=(lane>>4)*4+reg (t) (m89-verified)
    {
        unsigned short* BU  = (unsigned short*)(smem + BU_OFF);
        unsigned short* CHB = (unsigned short*)(smem + CH_OFF);
        const int s = wn * 16 + l15;
        const float biasB = sB_b[s], biasC = sC_b[s];
        #pragma unroll
        for (int mf = 0; mf < 4; ++mf) {
            #pragma unroll
            for (int q = 0; q < 4; ++q) {
                const int t = wm * 64 + mf * 16 + lg * 4 + q;
                const float u  = acc[mf][0][q];
                const float Bv = acc[mf][1][q] + biasB;
                const float Cv = acc[mf][2][q] + biasC;
                BU[t * 64 + s]   = f2b(Bv * u);
                CHB[swz64(t, s)] = f2b(Cv);
            }
        }
    }
    {
        const float w2 = (l15 < 8) ? sD2_w[l15] : 0.0f;
        const float b1 = (l15 < 8) ? sD1_b[l15] : 0.0f;
        const float b2 = sD2_b[0];
        #pragma unroll
        for (int q = 0; q < 4; ++q) {
            float z = accdt[q] + b1;
            float w = (z / (1.0f + expf(-z))) * w2;
            w = (l15 < 8) ? w : 0.0f;
            w += __shfl_xor(w, 1);
            w += __shfl_xor(w, 2);
            w += __shfl_xor(w, 4);
            if (l15 == 0) {
                float zz = w + b2;
                DTB[wid * 16 + lg * 4 + q] = (zz > 20.0f) ? zz : log1pf(expf(zz));
            }
        }
    }
    __syncthreads();

    // ---------------- Phase 2: scan (wave 0) || ROS0 pass-0 DMA (waves 1-7) ----------------
    if (tid < 64) {
        unsigned short* BU = (unsigned short*)(smem + BU_OFF);
        const int s = tid;
        float Pcv = 1.0f, cv = 0.0f, Hv = 0.0f;
        float* hout = Hseq + ((size_t)b * T_N * P_N + p) * S_N + s;
        float bn[4], dn[4];
        #pragma unroll
        for (int q = 0; q < 4; ++q) { bn[q] = b2f(BU[q * 64 + s]); dn[q] = DTB[q]; }
        for (int t0 = 0; t0 < T_N; t0 += 4) {
            float bc[4], dc[4];
            #pragma unroll
            for (int q = 0; q < 4; ++q) { bc[q] = bn[q]; dc[q] = dn[q]; }
            if (t0 + 4 < T_N) {
                #pragma unroll
                for (int q = 0; q < 4; ++q) {
                    bn[q] = b2f(BU[(t0 + 4 + q) * 64 + s]);
                    dn[q] = DTB[t0 + 4 + q];
                }
            }
            #pragma unroll
            for (int q = 0; q < 4; ++q) {
                const int t = t0 + q;
                const float Av = expf(dc[q] * la);
                const float bv = (1.0f - Av) * bc[q];
                Pcv *= fmaxf(Av, 1e-12f);                 // Pc = cumprod(max(A,eps))
                cv += bv * (1.0f / fmaxf(Pcv, 1e-12f));   // c += b * invP
                Hv = Pcv * (h0v + cv);
                hout[(size_t)t * P_N * S_N] = Hv;
                BU[t * 64 + s] = f2b(Hv);                 // H in place
            }
        }
        HT[((size_t)b * P_N + p) * S_N + s] = Hv;
    } else {
        for (int seg = wid - 1; seg < 16; seg += 7)
            gload16(roImgB + seg * 1024 + lane16, smem + ROS0_OFF + seg * 1024);
    }
    __syncthreads();   // drains ROS0 DMA + scan LDS writes

    // ---------------- CH = C * H, parallel ----------------
    {
        unsigned short* BU  = (unsigned short*)(smem + BU_OFF);
        unsigned short* CHB = (unsigned short*)(smem + CH_OFF);
        const int r = tid >> 2, c0 = (tid & 3) * 16;
        bf16x8 h0 = *(const bf16x8*)&BU[r * 64 + c0];
        bf16x8 h1 = *(const bf16x8*)&BU[r * 64 + c0 + 8];
        bf16x8 c8a = *(const bf16x8*)&CHB[swz64(r, c0)];
        bf16x8 c8b = *(const bf16x8*)&CHB[swz64(r, c0 + 8)];
        bf16x8 o0, o1;
        #pragma unroll
        for (int j = 0; j < 8; ++j) {
            o0[j] = (short)f2b(b2f((unsigned short)c8a[j]) * b2f((unsigned short)h0[j]));
            o1[j] = (short)f2b(b2f((unsigned short)c8b[j]) * b2f((unsigned short)h1[j]));
        }
        *(bf16x8*)&CHB[swz64(r, c0)]     = o0;
        *(bf16x8*)&CHB[swz64(r, c0 + 8)] = o1;
    }
    __syncthreads();

    // ---------------- Phase 3: Y = CH(128x64) x ro^T(64x512), operand-swapped MFMA ----------------
    // mfma(A=ro, B=CH): D row(lg,q)=d (consecutive), col(l15)=t -> float4 Y stores
    bf16x8 af0[4], af1[4];
    {
        unsigned short* CHB = (unsigned short*)(smem + CH_OFF);
        #pragma unroll
        for (int mf = 0; mf < 4; ++mf) {
            af0[mf] = *(const bf16x8*)&CHB[swz64(wm * 64 + mf * 16 + l15, lg * 8)];
            af1[mf] = *(const bf16x8*)&CHB[swz64(wm * 64 + mf * 16 + l15, 32 + lg * 8)];
        }
    }

    for (int pp = 0; pp < 4; ++pp) {
        unsigned short* cur = (unsigned short*)(smem + ((pp & 1) ? ROS1_OFF : ROS0_OFF));
        char*           nxt = smem + ((pp & 1) ? ROS0_OFF : ROS1_OFF);
        if (pp < 3) {
            gload16(roImgB + (pp + 1) * 16384 + wid * 2048 + lane16,        nxt + wid * 2048);
            gload16(roImgB + (pp + 1) * 16384 + wid * 2048 + 1024 + lane16, nxt + wid * 2048 + 1024);
        }
        f32x4 yacc[4][2];
        #pragma unroll
        for (int mf = 0; mf < 4; ++mf)
            #pragma unroll
            for (int nf = 0; nf < 2; ++nf)
                #pragma unroll
                for (int q = 0; q < 4; ++q) yacc[mf][nf][q] = 0.0f;
        #pragma unroll
        for (int nf = 0; nf < 2; ++nf) {
            bf16x8 bb0 = *(const bf16x8*)&cur[swz64(wn * 32 + nf * 16 + l15, lg * 8)];
            bf16x8 bb1 = *(const bf16x8*)&cur[swz64(wn * 32 + nf * 16 + l15, 32 + lg * 8)];
            #pragma unroll
            for (int mf = 0; mf < 4; ++mf) {
                yacc[mf][nf] = __builtin_amdgcn_mfma_f32_16x16x32_bf16(bb0, af0[mf], yacc[mf][nf], 0, 0, 0);
                yacc[mf][nf] = __builtin_amdgcn_mfma_f32_16x16x32_bf16(bb1, af1[mf], yacc[mf][nf], 0, 0, 0);
            }
        }
        #pragma unroll
        for (int mf = 0; mf < 4; ++mf) {
            const int t = wm * 64 + mf * 16 + l15;
            float* ybase = Y + (((size_t)b * T_N + t) * P_N + p) * D_N;
            #pragma unroll
            for (int nf = 0; nf < 2; ++nf) {
                const int d = pp * 128 + wn * 32 + nf * 16 + lg * 4;
                *(float4*)(ybase + d) = make_float4(yacc[mf][nf][0], yacc[mf][nf][1],
                                                    yacc[mf][nf][2], yacc[mf][nf][3]);
            }
        }
        if (pp < 3) __syncthreads();
    }
}

extern "C" void kernel_launch(void* const* d_in, const int* in_sizes, int n_in,
                              void* d_out, int out_size, void* d_ws, size_t ws_size,
                              hipStream_t stream) {
    const float* X     = (const float*)d_in[0];
    const float* H0    = (const float*)d_in[1];
    const float* a_hat = (const float*)d_in[2];
    const float* U_w   = (const float*)d_in[3];
    const float* sB_w  = (const float*)d_in[4];
    const float* sB_b  = (const float*)d_in[5];
    const float* sC_w  = (const float*)d_in[6];
    const float* sC_b  = (const float*)d_in[7];
    const float* sD1_w = (const float*)d_in[8];
    const float* sD1_b = (const float*)d_in[9];
    const float* sD2_w = (const float*)d_in[10];
    const float* sD2_b = (const float*)d_in[11];
    const float* ro_w  = (const float*)d_in[12];

    float* out   = (float*)d_out;
    float* HseqP = out;
    float* YP    = out + (size_t)B_N * T_N * P_N * S_N;
    float* HTP   = YP  + (size_t)B_N * T_N * P_N * D_N;

    unsigned short* wImg  = (unsigned short*)d_ws;                       // 262144 B
    unsigned short* roImg = (unsigned short*)((char*)d_ws + 262144);     // 65536 B

    hipLaunchKernelGGL(mamba_prep, dim3((WIMG_ELEMS + ROIMG_ELEMS) / 512), dim3(512), 0, stream,
                       U_w, sB_w, sC_w, sD1_w, ro_w, wImg, roImg);
    hipLaunchKernelGGL(mamba_mfma, dim3(B_N * P_N), dim3(NTH), 0, stream,
                       X, H0, a_hat, sB_b, sC_b, sD1_b, sD2_w, sD2_b,
                       wImg, roImg, HseqP, YP, HTP);
}

// Round 13
// 152.663 us; speedup vs baseline: 1.0332x; 1.0332x over previous
//
#include <hip/hip_runtime.h>
#include <hip/hip_bf16.h>
#include <math.h>

namespace {
constexpr int B_N = 4, T_N = 128, P_N = 256, D_N = 512, S_N = 64;
constexpr int NTH = 512;
constexpr int KC  = 32;
constexpr int NCH = D_N / KC;   // 16 k-chunks

// LDS (bytes). Liveness (barrier-protected):
//   phase1 k-loop : XS0 [0,8192) WS0 [8192,24576) XS1 [24576,32768) WS1 [32768,49152)
//   epilogue      : BU [0,16384) + CHB [16384,32768)            (XS*/WS* dead)
//   scan          : reads BU/DTB, writes HSEQ f32 [32768,65536) (WS1 dead)
//   post-scan     : ROS0 DMA -> [0,16384) (BU dead) || Hseq writeout + CH-mult (HSEQ,CHB)
//   phase3        : ROS0 [0,16384) / ROS1 [16384,32768) dbuf    (CHB dead after af-hoist)
constexpr int XS0_OFF = 0;       // bf16 [128][32] swz32
constexpr int WS0_OFF = 8192;    // bf16 [256][32] swz32 W image chunk (rows 200-255 zero)
constexpr int XS1_OFF = 24576;
constexpr int WS1_OFF = 32768;
constexpr int BU_OFF  = 0;       // bf16 [128][64] linear: (B+bias)*u
constexpr int CH_OFF  = 16384;   // bf16 [128][64] swz64: C+bias -> C*H
constexpr int HS_OFF  = 32768;   // f32  [128][64]: scan H output (full precision)
constexpr int ROS0_OFF= 0;       // bf16 [128][64] swz64 ro tile (phase 3)
constexpr int ROS1_OFF= 16384;
constexpr int DT_OFF  = 65536;   // f32 [128]
constexpr int LDS_BYTES = 66048; // 2 blocks/CU (132 KB <= 160 KB)

constexpr int WIMG_ELEMS  = NCH * 256 * 32;   // 16 x 16KB W chunk images
constexpr int ROIMG_ELEMS = 4 * 128 * 64;     // 4 x 16KB ro pass images
}

typedef short bf16x8 __attribute__((ext_vector_type(8)));
typedef float f32x4  __attribute__((ext_vector_type(4)));

__device__ __forceinline__ unsigned short f2b(float f) {
    unsigned int x = __float_as_uint(f);
    return (unsigned short)((x + 0x7FFFu + ((x >> 16) & 1u)) >> 16);  // RNE
}
__device__ __forceinline__ float b2f(unsigned short h) {
    return __uint_as_float(((unsigned int)h) << 16);
}
__device__ __forceinline__ unsigned int pk2(float lo, float hi) {
    union { __hip_bfloat162 h; unsigned int u; } cv;
    cv.h = __float22bfloat162_rn(float2{lo, hi});
    return cv.u;
}
__device__ __forceinline__ int swz32(int row, int col) {
    return row * 32 + (col ^ (((row >> 1) & 3) << 3));
}
__device__ __forceinline__ int swz64(int row, int col) {
    return row * 64 + (col ^ ((row & 7) << 3));
}
__device__ __forceinline__ void cvtstore8(unsigned short* dst, float4 a, float4 b) {
    uint4 r;
    r.x = pk2(a.x, a.y); r.y = pk2(a.z, a.w);
    r.z = pk2(b.x, b.y); r.w = pk2(b.z, b.w);
    *(uint4*)dst = r;
}
// async global->LDS DMA: per-lane global src, wave-uniform LDS dst (lane i -> dst+i*16)
__device__ __forceinline__ void gload16(const void* g, void* l) {
    __builtin_amdgcn_global_load_lds(
        (const __attribute__((address_space(1))) unsigned int*)g,
        (__attribute__((address_space(3))) unsigned int*)l, 16, 0, 0);
}

// ===== K0: build swizzled bf16 images of weights and ro in ws =====
__global__ __launch_bounds__(512) void mamba_prep(
    const float* __restrict__ U_w, const float* __restrict__ sB_w,
    const float* __restrict__ sC_w, const float* __restrict__ sD1_w,
    const float* __restrict__ ro_w,
    unsigned short* __restrict__ wImg, unsigned short* __restrict__ roImg)
{
    const int idx = blockIdx.x * 512 + threadIdx.x;
    if (idx < WIMG_ELEMS) {
        const int kc = idx >> 13, rem = idx & 8191, r = rem >> 5, c = rem & 31;
        float v = 0.0f;
        if (r < 192) {
            const int g = r >> 4, w = r & 15, tr = g % 3, sb = g / 3;
            const float* base = (tr == 0) ? U_w : (tr == 1) ? sB_w : sC_w;
            v = base[(size_t)(sb * 16 + w) * D_N + kc * KC + c];
        } else if (r < 200) {
            v = sD1_w[(size_t)(r - 192) * D_N + kc * KC + c];
        }
        wImg[kc * 8192 + swz32(r, c)] = f2b(v);
    } else if (idx < WIMG_ELEMS + ROIMG_ELEMS) {
        const int j = idx - WIMG_ELEMS;
        const int pp = j >> 13, rem = j & 8191, r = rem >> 6, c = rem & 63;
        roImg[pp * 8192 + swz64(r, c)] = f2b(ro_w[(size_t)(pp * 128 + r) * S_N + c]);
    }
}

// ===== fused kernel =====
__global__ __launch_bounds__(NTH, 4) void mamba_mfma(
    const float* __restrict__ X, const float* __restrict__ H0,
    const float* __restrict__ a_hat,
    const float* __restrict__ sB_b, const float* __restrict__ sC_b,
    const float* __restrict__ sD1_b, const float* __restrict__ sD2_w,
    const float* __restrict__ sD2_b,
    const unsigned short* __restrict__ wImg, const unsigned short* __restrict__ roImg,
    float* __restrict__ Hseq, float* __restrict__ Y, float* __restrict__ HT)
{
    __shared__ __align__(16) char smem[LDS_BYTES];
    float* DTB = (float*)(smem + DT_OFF);

    const int tid  = threadIdx.x;
    const int lane = tid & 63;
    const int wid  = tid >> 6;
    const int wm   = wid >> 2;     // 0..1
    const int wn   = wid & 3;      // 0..3
    const int l15  = lane & 15;
    const int lg   = lane >> 4;    // 0..3
    const int lane16 = lane * 16;
    const int b    = blockIdx.x >> 8;
    const int p    = blockIdx.x & 255;
    const char* wImgB  = (const char*)wImg;
    const char* roImgB = (const char*)roImg;

    // scan-wave constants hoisted (issued early; hide under phase 1)
    const float la  = (tid < 64) ? -expf(a_hat[tid]) : 0.0f;
    const float h0v = (tid < 64) ? H0[((size_t)b * P_N + p) * S_N + tid] : 0.0f;

    // ---------------- Phase 1: projections, M=128(t) N=192(+8 dt) K=512 ----------------
    f32x4 acc[4][3];
    f32x4 accdt;
    #pragma unroll
    for (int q = 0; q < 4; ++q) accdt[q] = 0.0f;
    #pragma unroll
    for (int mf = 0; mf < 4; ++mf)
        #pragma unroll
        for (int nf = 0; nf < 3; ++nf)
            #pragma unroll
            for (int q = 0; q < 4; ++q) acc[mf][nf][q] = 0.0f;

    // X staging: 128 rows x 4 quads of 8 f32 (cvt on write); 2-deep reg prefetch
    const int xr = tid >> 2, xq = tid & 3;
    const float* xsrc = X + (((size_t)b * T_N + xr) * P_N + p) * D_N + xq * 8;
    const int xoff = swz32(xr, xq * 8);

    // prologue: chunk0 -> XS0 (reg roundtrip), W0 via DMA; issue chunk-1 X loads
    float4 xA, xB;
    {
        float4 t0 = *(const float4*)(xsrc), t1 = *(const float4*)(xsrc + 4);
        cvtstore8((unsigned short*)(smem + XS0_OFF) + xoff, t0, t1);
        gload16(wImgB + wid * 2048 + lane16,        smem + WS0_OFF + wid * 2048);
        gload16(wImgB + wid * 2048 + 1024 + lane16, smem + WS0_OFF + wid * 2048 + 1024);
        const float* n1 = xsrc + KC;
        xA = *(const float4*)(n1); xB = *(const float4*)(n1 + 4);
    }
    __syncthreads();

    const int kb = lg * 8;
    #pragma unroll 2
    for (int kc = 0; kc < NCH; ++kc) {
        unsigned short* XSc = (unsigned short*)(smem + ((kc & 1) ? XS1_OFF : XS0_OFF));
        unsigned short* WSc = (unsigned short*)(smem + ((kc & 1) ? WS1_OFF : WS0_OFF));
        char*           XSn = smem + ((kc & 1) ? XS0_OFF : XS1_OFF);
        char*           WSn = smem + ((kc & 1) ? WS0_OFF : WS1_OFF);
        if (kc + 1 < NCH) {
            cvtstore8((unsigned short*)XSn + xoff, xA, xB);
            gload16(wImgB + (kc + 1) * 16384 + wid * 2048 + lane16,        WSn + wid * 2048);
            gload16(wImgB + (kc + 1) * 16384 + wid * 2048 + 1024 + lane16, WSn + wid * 2048 + 1024);
        }
        if (kc + 2 < NCH) {
            const float* nx = xsrc + (kc + 2) * KC;
            xA = *(const float4*)(nx); xB = *(const float4*)(nx + 4);
        }
        __builtin_amdgcn_s_setprio(1);
        bf16x8 a[4];
        #pragma unroll
        for (int mf = 0; mf < 4; ++mf)
            a[mf] = *(const bf16x8*)&XSc[swz32(wm * 64 + mf * 16 + l15, kb)];
        #pragma unroll
        for (int nf = 0; nf < 3; ++nf) {
            bf16x8 bb = *(const bf16x8*)&WSc[swz32(wn * 48 + nf * 16 + l15, kb)];
            #pragma unroll
            for (int mf = 0; mf < 4; ++mf)
                acc[mf][nf] = __builtin_amdgcn_mfma_f32_16x16x32_bf16(a[mf], bb, acc[mf][nf], 0, 0, 0);
        }
        {   // dt frag (W rows 192-199 sD1, 200-207 baked zeros)
            bf16x8 adt = *(const bf16x8*)&XSc[swz32(wid * 16 + l15, kb)];
            bf16x8 bd  = *(const bf16x8*)&WSc[swz32(192 + l15, kb)];
            accdt = __builtin_amdgcn_mfma_f32_16x16x32_bf16(adt, bd, accdt, 0, 0, 0);
        }
        __builtin_amdgcn_s_setprio(0);
        __syncthreads();
    }

    // ---------------- Phase 1 epilogue ----------------
    // C/D frag: col=lane&15 (s), row=(lane>>4)*4+reg (t) (m89-verified)
    {
        unsigned short* BU  = (unsigned short*)(smem + BU_OFF);
        unsigned short* CHB = (unsigned short*)(smem + CH_OFF);
        const int s = wn * 16 + l15;
        const float biasB = sB_b[s], biasC = sC_b[s];
        #pragma unroll
        for (int mf = 0; mf < 4; ++mf) {
            #pragma unroll
            for (int q = 0; q < 4; ++q) {
                const int t = wm * 64 + mf * 16 + lg * 4 + q;
                const float u  = acc[mf][0][q];
                const float Bv = acc[mf][1][q] + biasB;
                const float Cv = acc[mf][2][q] + biasC;
                BU[t * 64 + s]   = f2b(Bv * u);
                CHB[swz64(t, s)] = f2b(Cv);
            }
        }
    }
    {
        const float w2 = (l15 < 8) ? sD2_w[l15] : 0.0f;
        const float b1 = (l15 < 8) ? sD1_b[l15] : 0.0f;
        const float b2 = sD2_b[0];
        #pragma unroll
        for (int q = 0; q < 4; ++q) {
            float z = accdt[q] + b1;
            float w = (z / (1.0f + expf(-z))) * w2;
            w = (l15 < 8) ? w : 0.0f;
            w += __shfl_xor(w, 1);
            w += __shfl_xor(w, 2);
            w += __shfl_xor(w, 4);
            if (l15 == 0) {
                float zz = w + b2;
                DTB[wid * 16 + lg * 4 + q] = (zz > 20.0f) ? zz : log1pf(expf(zz));
            }
        }
    }
    __syncthreads();

    // ---------------- Phase 2: scan (wave 0), LDS-only stores ----------------
    if (tid < 64) {
        unsigned short* BU   = (unsigned short*)(smem + BU_OFF);
        float*          HSEQ = (float*)(smem + HS_OFF);
        const int s = tid;
        float Pcv = 1.0f, cv = 0.0f, Hv = 0.0f;
        float bn[4], dn[4];
        #pragma unroll
        for (int q = 0; q < 4; ++q) { bn[q] = b2f(BU[q * 64 + s]); dn[q] = DTB[q]; }
        for (int t0 = 0; t0 < T_N; t0 += 4) {
            float bc[4], dc[4];
            #pragma unroll
            for (int q = 0; q < 4; ++q) { bc[q] = bn[q]; dc[q] = dn[q]; }
            if (t0 + 4 < T_N) {
                #pragma unroll
                for (int q = 0; q < 4; ++q) {
                    bn[q] = b2f(BU[(t0 + 4 + q) * 64 + s]);
                    dn[q] = DTB[t0 + 4 + q];
                }
            }
            #pragma unroll
            for (int q = 0; q < 4; ++q) {
                const float Av = expf(dc[q] * la);
                const float bv = (1.0f - Av) * bc[q];
                Pcv *= fmaxf(Av, 1e-12f);                 // Pc = cumprod(max(A,eps))
                cv += bv * (1.0f / fmaxf(Pcv, 1e-12f));   // c += b * invP
                Hv = Pcv * (h0v + cv);
                HSEQ[(t0 + q) * 64 + s] = Hv;             // f32, LDS only
            }
        }
        HT[((size_t)b * P_N + p) * S_N + s] = Hv;
    }
    __syncthreads();   // scan HSEQ writes visible; BU now dead

    // ---------------- post-scan: ROS0 DMA || Hseq writeout + CH = C*H (f32 H) ----------------
    // ROS0 pass-0 tile DMA into dead BU region (drained by next barrier)
    gload16(roImgB + wid * 2048 + lane16,        smem + ROS0_OFF + wid * 2048);
    gload16(roImgB + wid * 2048 + 1024 + lane16, smem + ROS0_OFF + wid * 2048 + 1024);
    {
        float*          HSEQ = (float*)(smem + HS_OFF);
        unsigned short* CHB  = (unsigned short*)(smem + CH_OFF);
        const int r  = tid >> 2;
        const int c0 = (((tid & 3) + r) & 3) * 16;   // row-rotated column -> spread LDS banks
        float4 h0 = *(const float4*)&HSEQ[r * 64 + c0];
        float4 h1 = *(const float4*)&HSEQ[r * 64 + c0 + 4];
        float4 h2 = *(const float4*)&HSEQ[r * 64 + c0 + 8];
        float4 h3 = *(const float4*)&HSEQ[r * 64 + c0 + 12];
        float* hout = Hseq + (((size_t)b * T_N + r) * P_N + p) * S_N + c0;
        *(float4*)(hout)      = h0;
        *(float4*)(hout + 4)  = h1;
        *(float4*)(hout + 8)  = h2;
        *(float4*)(hout + 12) = h3;
        bf16x8 ca = *(const bf16x8*)&CHB[swz64(r, c0)];
        bf16x8 cb = *(const bf16x8*)&CHB[swz64(r, c0 + 8)];
        bf16x8 oa, ob;
        oa[0] = (short)f2b(b2f((unsigned short)ca[0]) * h0.x);
        oa[1] = (short)f2b(b2f((unsigned short)ca[1]) * h0.y);
        oa[2] = (short)f2b(b2f((unsigned short)ca[2]) * h0.z);
        oa[3] = (short)f2b(b2f((unsigned short)ca[3]) * h0.w);
        oa[4] = (short)f2b(b2f((unsigned short)ca[4]) * h1.x);
        oa[5] = (short)f2b(b2f((unsigned short)ca[5]) * h1.y);
        oa[6] = (short)f2b(b2f((unsigned short)ca[6]) * h1.z);
        oa[7] = (short)f2b(b2f((unsigned short)ca[7]) * h1.w);
        ob[0] = (short)f2b(b2f((unsigned short)cb[0]) * h2.x);
        ob[1] = (short)f2b(b2f((unsigned short)cb[1]) * h2.y);
        ob[2] = (short)f2b(b2f((unsigned short)cb[2]) * h2.z);
        ob[3] = (short)f2b(b2f((unsigned short)cb[3]) * h2.w);
        ob[4] = (short)f2b(b2f((unsigned short)cb[4]) * h3.x);
        ob[5] = (short)f2b(b2f((unsigned short)cb[5]) * h3.y);
        ob[6] = (short)f2b(b2f((unsigned short)cb[6]) * h3.z);
        ob[7] = (short)f2b(b2f((unsigned short)cb[7]) * h3.w);
        *(bf16x8*)&CHB[swz64(r, c0)]     = oa;
        *(bf16x8*)&CHB[swz64(r, c0 + 8)] = ob;
    }
    __syncthreads();   // drains ROS0 DMA + CHB updates

    // ---------------- Phase 3: Y = CH(128x64) x ro^T(64x512), operand-swapped ----------------
    // mfma(A=ro, B=CH): D row(lg,q)=d (consecutive), col(l15)=t -> float4 Y stores
    bf16x8 af0[4], af1[4];
    {
        unsigned short* CHB = (unsigned short*)(smem + CH_OFF);
        #pragma unroll
        for (int mf = 0; mf < 4; ++mf) {
            af0[mf] = *(const bf16x8*)&CHB[swz64(wm * 64 + mf * 16 + l15, lg * 8)];
            af1[mf] = *(const bf16x8*)&CHB[swz64(wm * 64 + mf * 16 + l15, 32 + lg * 8)];
        }
    }
    __syncthreads();   // all af-hoist reads done before ROS1 (=CHB region) is overwritten

    for (int pp = 0; pp < 4; ++pp) {
        unsigned short* cur = (unsigned short*)(smem + ((pp & 1) ? ROS1_OFF : ROS0_OFF));
        char*           nxt = smem + ((pp & 1) ? ROS0_OFF : ROS1_OFF);
        if (pp < 3) {
            gload16(roImgB + (pp + 1) * 16384 + wid * 2048 + lane16,        nxt + wid * 2048);
            gload16(roImgB + (pp + 1) * 16384 + wid * 2048 + 1024 + lane16, nxt + wid * 2048 + 1024);
        }
        f32x4 yacc[4][2];
        #pragma unroll
        for (int mf = 0; mf < 4; ++mf)
            #pragma unroll
            for (int nf = 0; nf < 2; ++nf)
                #pragma unroll
                for (int q = 0; q < 4; ++q) yacc[mf][nf][q] = 0.0f;
        #pragma unroll
        for (int nf = 0; nf < 2; ++nf) {
            bf16x8 bb0 = *(const bf16x8*)&cur[swz64(wn * 32 + nf * 16 + l15, lg * 8)];
            bf16x8 bb1 = *(const bf16x8*)&cur[swz64(wn * 32 + nf * 16 + l15, 32 + lg * 8)];
            #pragma unroll
            for (int mf = 0; mf < 4; ++mf) {
                yacc[mf][nf] = __builtin_amdgcn_mfma_f32_16x16x32_bf16(bb0, af0[mf], yacc[mf][nf], 0, 0, 0);
                yacc[mf][nf] = __builtin_amdgcn_mfma_f32_16x16x32_bf16(bb1, af1[mf], yacc[mf][nf], 0, 0, 0);
            }
        }
        #pragma unroll
        for (int mf = 0; mf < 4; ++mf) {
            const int t = wm * 64 + mf * 16 + l15;
            float* ybase = Y + (((size_t)b * T_N + t) * P_N + p) * D_N;
            #pragma unroll
            for (int nf = 0; nf < 2; ++nf) {
                const int d = pp * 128 + wn * 32 + nf * 16 + lg * 4;
                *(float4*)(ybase + d) = make_float4(yacc[mf][nf][0], yacc[mf][nf][1],
                                                    yacc[mf][nf][2], yacc[mf][nf][3]);
            }
        }
        if (pp < 3) __syncthreads();
    }
}

extern "C" void kernel_launch(void* const* d_in, const int* in_sizes, int n_in,
                              void* d_out, int out_size, void* d_ws, size_t ws_size,
                              hipStream_t stream) {
    const float* X     = (const float*)d_in[0];
    const float* H0    = (const float*)d_in[1];
    const float* a_hat = (const float*)d_in[2];
    const float* U_w   = (const float*)d_in[3];
    const float* sB_w  = (const float*)d_in[4];
    const float* sB_b  = (const float*)d_in[5];
    const float* sC_w  = (const float*)d_in[6];
    const float* sC_b  = (const float*)d_in[7];
    const float* sD1_w = (const float*)d_in[8];
    const float* sD1_b = (const float*)d_in[9];
    const float* sD2_w = (const float*)d_in[10];
    const float* sD2_b = (const float*)d_in[11];
    const float* ro_w  = (const float*)d_in[12];

    float* out   = (float*)d_out;
    float* HseqP = out;
    float* YP    = out + (size_t)B_N * T_N * P_N * S_N;
    float* HTP   = YP  + (size_t)B_N * T_N * P_N * D_N;

    unsigned short* wImg  = (unsigned short*)d_ws;                       // 262144 B
    unsigned short* roImg = (unsigned short*)((char*)d_ws + 262144);     // 65536 B

    hipLaunchKernelGGL(mamba_prep, dim3((WIMG_ELEMS + ROIMG_ELEMS) / 512), dim3(512), 0, stream,
                       U_w, sB_w, sC_w, sD1_w, ro_w, wImg, roImg);
    hipLaunchKernelGGL(mamba_mfma, dim3(B_N * P_N), dim3(NTH), 0, stream,
                       X, H0, a_hat, sB_b, sC_b, sD1_b, sD2_w, sD2_b,
                       wImg, roImg, HseqP, YP, HTP);
}